// Round 9
// baseline (247.349 us; speedup 1.0000x reference)
//
#include <hip/hip_runtime.h>

#define NE 8
#define HW 128
#define OUT_HW 384
#define C1 64
#define C2 32
#define C3 9

typedef __attribute__((ext_vector_type(4))) float f32x4;
typedef __attribute__((ext_vector_type(8))) short bf16x8s;
typedef __attribute__((ext_vector_type(4))) unsigned short u16x4;

// Prepacked conv1 weights, bf16: [e][oc=64][tap=32 (25 valid, rest 0)]
__device__ __align__(16) unsigned short g_w1b[NE * C1 * 32];
// Prepacked conv2 weights, bf16: [e][koff(ky*3+kx)][oc=32][ic=64]
__device__ __align__(16) unsigned short g_w2b[NE * 9 * C2 * C1];
// Prepacked conv3 weights, bf16: [e][koff][oc=16 (9 valid)][ic=32]
__device__ __align__(16) unsigned short g_w3b[NE * 9 * 16 * 32];

__device__ __forceinline__ unsigned short f2bf(float f) {
    unsigned u = __builtin_bit_cast(unsigned, f);
    u += 0x7fffu + ((u >> 16) & 1u);          // round-nearest-even
    return (unsigned short)(u >> 16);
}

__global__ void repack_weights_kernel(const float* __restrict__ w1,
                                      const float* __restrict__ w2,
                                      const float* __restrict__ w3) {
    int i = blockIdx.x * 256 + threadIdx.x;
    const int n2 = NE * C2 * C1 * 9;          // 36864
    const int n1 = NE * C1 * 32;              // 16384
    const int n3 = NE * 9 * 16 * 32;          // 36864
    if (i < n2) {
        // source: [e][oc][ic][ky][kx] -> dest [e][koff][oc][ic]
        int e = i / (C2 * C1 * 9);
        int r = i - e * (C2 * C1 * 9);
        int oc = r / (C1 * 9); r -= oc * (C1 * 9);
        int ic = r / 9;
        int koff = r - ic * 9;
        g_w2b[((e * 9 + koff) * C2 + oc) * C1 + ic] = f2bf(w2[i]);
    } else if (i < n2 + n1) {
        int j = i - n2;                        // [e][oc][tap]
        int tap = j & 31;
        int eoc = j >> 5;                      // e*64+oc
        float v = (tap < 25) ? w1[eoc * 25 + tap] : 0.f;
        g_w1b[j] = f2bf(v);
    } else if (i < n2 + n1 + n3) {
        int j = i - n2 - n1;
        int e = j / (9 * 16 * 32);
        int r = j - e * (9 * 16 * 32);
        int koff = r / 512; r -= koff * 512;
        int oc = r / 32;
        int ic = r - oc * 32;
        float v = 0.f;
        if (oc < C3) v = w3[((e * C3 + oc) * 32 + ic) * 9 + koff];
        g_w3b[((e * 9 + koff) * 16 + oc) * 32 + ic] = f2bf(v);
    }
}

__device__ __forceinline__ float fast_tanh(float x) {
    float ax = fabsf(x);
    float ex = __expf(2.0f * ax);                       // inf-safe
    float tv = 1.0f - 2.0f * __builtin_amdgcn_rcpf(ex + 1.0f);
    return copysignf(tv, x);
}

__launch_bounds__(256, 5)
__global__ void espcn_fused_kernel(const float* __restrict__ x,
                                   const int* __restrict__ ci,
                                   const float* __restrict__ b1,
                                   const float* __restrict__ b2,
                                   const float* __restrict__ b3,
                                   float* __restrict__ out) {
    // LDS pool with liveness-based aliasing (31040 B -> 5 blocks/CU):
    //   [0,1088):      xs float[16][17]           live phase 0 -> 0.5
    //   [1088,12608):  imc 144x80B                live 0.5 -> 1
    //                  h2b 100x64B (aliased)      live 2 -> 3
    //   [12608,31040): h1s 144x128B               live 1 -> 2
    //                  outT 24x28 f32 (aliased)   live 3 -> 4
    __shared__ __align__(16) char ldsp[31040];
    float (*xs)[17]   = (float(*)[17])ldsp;
    char* imc         = ldsp + 1088;
    char* h2b         = ldsp + 1088;
    char* h1s         = ldsp + 12608;
    float (*outT)[28] = (float(*)[28])(ldsp + 12608);

    const int tx = blockIdx.x, ty = blockIdx.y, b = blockIdx.z;
    const int R0 = ty * 8, C0 = tx * 8;
    int e = ci[b];
    e = __builtin_amdgcn_readfirstlane(e);                  // force SGPR: scalar weight loads
    const int t = threadIdx.x;
    const int lane = t & 63, wave = t >> 6;
    const int g = lane >> 4, r16 = lane & 15;

    // ---- phase 0: stage x patch rows [R0-4, R0+12), cols [C0-4, C0+12) ----
    {
        int i = t >> 4, j = t & 15;
        int gy = R0 - 4 + i, gx = C0 - 4 + j;
        float v = 0.f;
        if (gy >= 0 && gy < HW && gx >= 0 && gx < HW)
            v = x[(b * HW + gy) * HW + gx];
        xs[i][j] = v;
    }
    __syncthreads();

    // ---- phase 0.5: build im2col: 144 px x 16 tap-pairs (u32 writes) ----
    {
        #pragma unroll
        for (int q = 0; q < 9; ++q) {
            int idx = q * 256 + t;             // [0, 2304)
            int p = idx >> 4, w = idx & 15;
            int i = p / 12, j = p - i * 12;
            int tap0 = 2 * w, tap1 = 2 * w + 1;
            unsigned short lo = 0, hi = 0;
            if (tap0 < 25) lo = f2bf(xs[i + tap0 / 5][j + tap0 % 5]);
            if (tap1 < 25) hi = f2bf(xs[i + tap1 / 5][j + tap1 % 5]);
            *(unsigned*)(imc + p * 80 + w * 4) = (unsigned)lo | ((unsigned)hi << 16);
        }
    }
    __syncthreads();

    // ---- phase 1: conv1 as MFMA, SWAPPED: M=oc(64, tile=wave), N=pixel(144), K=32 ----
    // D: col(lane)=pixel, rows=4 consecutive oc per thread -> packed b64 stores.
    {
        const unsigned short* w1e = g_w1b + e * C1 * 32;
        // A-frag (weights): lane holds row r16 (oc = wave*16+r16), k = g*8..g*8+7
        bf16x8s W = *(const bf16x8s*)(w1e + (wave * 16 + r16) * 32 + g * 8);
        const int oc0 = wave * 16 + g * 4;       // this thread's 4 D-rows (oc)
        f32x4 bias4 = *(const f32x4*)(b1 + e * C1 + oc0);
        #pragma unroll
        for (int mt = 0; mt < 9; ++mt) {
            // B-frag (im2col): lane holds col r16 (pixel = mt*16+r16), k = g*8..
            bf16x8s I = *(const bf16x8s*)(imc + (mt * 16 + r16) * 80 + g * 16);
            f32x4 acc = {0.f, 0.f, 0.f, 0.f};
            acc = __builtin_amdgcn_mfma_f32_16x16x32_bf16(W, I, acc, 0, 0, 0);
            int p = mt * 16 + r16;               // pixel this thread's 4 oc belong to
            int r = p / 12, jj = p - r * 12;
            int gy = R0 - 2 + r, gx = C0 - 2 + jj;
            bool in = (gy >= 0 && gy < HW && gx >= 0 && gx < HW);
            u16x4 hv;
            #pragma unroll
            for (int q = 0; q < 4; ++q)
                hv[q] = f2bf(in ? fast_tanh(acc[q] + bias4[q]) : 0.f);
            int off = (p << 7) + ((wave * 32 + g * 8) ^ ((p & 7) << 4));
            *(u16x4*)(h1s + off) = hv;           // ds_write_b64
        }
    }
    __syncthreads();

    // ---- phase 2: conv2 as MFMA, SWAPPED: M=oc(32, 2 tiles), N=pixel(128 pad), K=576 ----
    {
        const unsigned short* w2e = g_w2b + e * 9 * C2 * C1;
        int ps0 = wave * 32 + r16;       if (ps0 > 99) ps0 = 99;
        int ps1 = wave * 32 + 16 + r16;  if (ps1 > 99) ps1 = 99;
        const int ab0 = (ps0 / 10) * 12 + (ps0 % 10);
        const int ab1 = (ps1 / 10) * 12 + (ps1 % 10);
        f32x4 acc00 = {0.f, 0.f, 0.f, 0.f}, acc01 = {0.f, 0.f, 0.f, 0.f};
        f32x4 acc10 = {0.f, 0.f, 0.f, 0.f}, acc11 = {0.f, 0.f, 0.f, 0.f};
        const int laneB = (r16 * C1 + g * 8);          // weight A-frag: row=oc=r16
        #pragma unroll
        for (int s = 0; s < 18; ++s) {
            const int koff = s >> 1;
            const int drow = (koff / 3) * 12 + (koff % 3);
            const int icoff2 = ((s & 1) * 32 + g * 8) * 2;
            int r0 = ab0 + drow, r1 = ab1 + drow;
            int o0 = ((r0 << 7) + icoff2) ^ ((r0 & 7) << 4);
            int o1 = ((r1 << 7) + icoff2) ^ ((r1 & 7) << 4);
            bf16x8s A0 = *(const bf16x8s*)(h1s + o0);   // h1 pixels (B-operand)
            bf16x8s A1 = *(const bf16x8s*)(h1s + o1);
            const unsigned short* wp = w2e + koff * C2 * C1 + (s & 1) * 32;
            bf16x8s B0 = *(const bf16x8s*)(wp + laneB);              // oc tile 0 (A-operand)
            bf16x8s B1 = *(const bf16x8s*)(wp + 16 * C1 + laneB);    // oc tile 1
            acc00 = __builtin_amdgcn_mfma_f32_16x16x32_bf16(B0, A0, acc00, 0, 0, 0);
            acc01 = __builtin_amdgcn_mfma_f32_16x16x32_bf16(B1, A0, acc01, 0, 0, 0);
            acc10 = __builtin_amdgcn_mfma_f32_16x16x32_bf16(B0, A1, acc10, 0, 0, 0);
            acc11 = __builtin_amdgcn_mfma_f32_16x16x32_bf16(B1, A1, acc11, 0, 0, 0);
        }
        // D: col=pixel (r16), rows=4 consecutive oc -> packed b64 stores per oc-tile.
        const float* b2e = b2 + e * C2;
        f32x4 bias0 = *(const f32x4*)(b2e + g * 4);
        f32x4 bias1 = *(const f32x4*)(b2e + 16 + g * 4);
        #pragma unroll
        for (int mm = 0; mm < 2; ++mm) {
            f32x4 a0 = mm ? acc10 : acc00;       // oc tile 0
            f32x4 a1 = mm ? acc11 : acc01;       // oc tile 1
            int pd = wave * 32 + mm * 16 + r16;
            if (pd < 100) {
                int y = pd / 10, xq2 = pd - y * 10;
                int gy = R0 - 1 + y, gx = C0 - 1 + xq2;
                bool in = (gy >= 0 && gy < HW && gx >= 0 && gx < HW);
                u16x4 h0, h1;
                #pragma unroll
                for (int q = 0; q < 4; ++q) {
                    h0[q] = f2bf(in ? fast_tanh(a0[q] + bias0[q]) : 0.f);
                    h1[q] = f2bf(in ? fast_tanh(a1[q] + bias1[q]) : 0.f);
                }
                int swz = (pd & 3) << 4;
                *(u16x4*)(h2b + (pd << 6) + ((g * 8) ^ swz)) = h0;
                *(u16x4*)(h2b + (pd << 6) + ((32 + g * 8) ^ swz)) = h1;
            }
        }
    }
    __syncthreads();

    // ---- phase 3: conv3 (3x3, 32->9 pad 16) as bf16 MFMA -> LDS out tile ----
    // M = 64 output pixels (4 tiles, one per wave), N = 16 (9 valid), K = 288 (9 steps).
    {
        const unsigned short* w3e = g_w3b + e * 9 * 16 * 32;
        const int pxA = wave * 16 + r16;            // A-row pixel
        const int oyA = pxA >> 3, oxA = pxA & 7;
        f32x4 acc = {0.f, 0.f, 0.f, 0.f};
        #pragma unroll
        for (int s = 0; s < 9; ++s) {
            const int ky = s / 3, kx = s % 3;
            int p = (oyA + ky) * 10 + (oxA + kx);
            int offA = (p << 6) + ((g * 16) ^ ((p & 3) << 4));
            bf16x8s A = *(const bf16x8s*)(h2b + offA);
            bf16x8s B = *(const bf16x8s*)(w3e + (s * 16 + r16) * 32 + g * 8);
            acc = __builtin_amdgcn_mfma_f32_16x16x32_bf16(A, B, acc, 0, 0, 0);
        }
        // D: row (pixel-in-tile) = g*4+q, col (oc) = r16.  Stage into LDS tile.
        if (r16 < C3) {
            float bias = b3[e * C3 + r16];
            #pragma unroll
            for (int q = 0; q < 4; ++q) {
                int pxd = wave * 16 + g * 4 + q;
                int oyd = pxd >> 3, oxd = pxd & 7;
                outT[oyd * 3 + r16 / 3][oxd * 3 + r16 % 3] = acc[q] + bias;
            }
        }
    }
    __syncthreads();

    // ---- phase 4: coalesced output write: 24 rows x 6 float4 (96 B/row) ----
    if (t < 144) {
        int row = t / 6, c4 = t - row * 6;
        f32x4 v = *(const f32x4*)&outT[row][c4 * 4];
        int gr = R0 * 3 + row;              // 24*ty + row
        int gc = C0 * 3 + c4 * 4;           // 24*tx + 4*c4
        *(f32x4*)&out[(b * OUT_HW + gr) * OUT_HW + gc] = v;
    }
}

extern "C" void kernel_launch(void* const* d_in, const int* in_sizes, int n_in,
                              void* d_out, int out_size, void* d_ws, size_t ws_size,
                              hipStream_t stream) {
    const float* x  = (const float*)d_in[0];
    const int*   ci = (const int*)  d_in[1];
    const float* w1 = (const float*)d_in[2];
    const float* b1 = (const float*)d_in[3];
    const float* w2 = (const float*)d_in[4];
    const float* b2 = (const float*)d_in[5];
    const float* w3 = (const float*)d_in[6];
    const float* b3 = (const float*)d_in[7];
    float* out = (float*)d_out;

    {
        const int total = NE * C2 * C1 * 9 + NE * C1 * 32 + NE * 9 * 16 * 32;
        repack_weights_kernel<<<(total + 255) / 256, 256, 0, stream>>>(w1, w2, w3);
    }
    {
        dim3 grid(HW / 8, HW / 8, 32);
        espcn_fused_kernel<<<grid, 256, 0, stream>>>(x, ci, b1, b2, b3, out);
    }
}

// Round 10
// 246.897 us; speedup vs baseline: 1.0018x; 1.0018x over previous
//
#include <hip/hip_runtime.h>

#define NE 8
#define HW 128
#define OUT_HW 384
#define C1 64
#define C2 32
#define C3 9

typedef __attribute__((ext_vector_type(4))) float f32x4;
typedef __attribute__((ext_vector_type(8))) short bf16x8s;
typedef __attribute__((ext_vector_type(4))) unsigned short u16x4;

// Prepacked conv1 weights, bf16: [e][oc=64][tap=32 (25 valid, rest 0)]
__device__ __align__(16) unsigned short g_w1b[NE * C1 * 32];
// Prepacked conv2 weights, bf16: [e][koff(ky*3+kx)][oc=32][ic=64]
__device__ __align__(16) unsigned short g_w2b[NE * 9 * C2 * C1];
// Prepacked conv3 weights, bf16: [e][koff][oc=16 (9 valid)][ic=32]
__device__ __align__(16) unsigned short g_w3b[NE * 9 * 16 * 32];

__device__ __forceinline__ unsigned short f2bf(float f) {
    unsigned u = __builtin_bit_cast(unsigned, f);
    u += 0x7fffu + ((u >> 16) & 1u);          // round-nearest-even
    return (unsigned short)(u >> 16);
}

__global__ void repack_weights_kernel(const float* __restrict__ w1,
                                      const float* __restrict__ w2,
                                      const float* __restrict__ w3) {
    int i = blockIdx.x * 256 + threadIdx.x;
    const int n2 = NE * C2 * C1 * 9;          // 36864
    const int n1 = NE * C1 * 32;              // 16384
    const int n3 = NE * 9 * 16 * 32;          // 36864
    if (i < n2) {
        // source: [e][oc][ic][ky][kx] -> dest [e][koff][oc][ic]
        int e = i / (C2 * C1 * 9);
        int r = i - e * (C2 * C1 * 9);
        int oc = r / (C1 * 9); r -= oc * (C1 * 9);
        int ic = r / 9;
        int koff = r - ic * 9;
        g_w2b[((e * 9 + koff) * C2 + oc) * C1 + ic] = f2bf(w2[i]);
    } else if (i < n2 + n1) {
        int j = i - n2;                        // [e][oc][tap]
        int tap = j & 31;
        int eoc = j >> 5;                      // e*64+oc
        float v = (tap < 25) ? w1[eoc * 25 + tap] : 0.f;
        g_w1b[j] = f2bf(v);
    } else if (i < n2 + n1 + n3) {
        int j = i - n2 - n1;
        int e = j / (9 * 16 * 32);
        int r = j - e * (9 * 16 * 32);
        int koff = r / 512; r -= koff * 512;
        int oc = r / 32;
        int ic = r - oc * 32;
        float v = 0.f;
        if (oc < C3) v = w3[((e * C3 + oc) * 32 + ic) * 9 + koff];
        g_w3b[((e * 9 + koff) * 16 + oc) * 32 + ic] = f2bf(v);
    }
}

// tanh(x) = 1 - 2/(1+e^{2x}).  exp2(+inf)->inf: rcp->0 -> +1; exp2(-inf)->0 -> -1.
// Branch/sign-handling free: 5 VALU (2 trans).
__device__ __forceinline__ float fast_tanh(float x) {
    float u = __builtin_amdgcn_exp2f(x * 2.88539008f);   // e^{2x}
    return 1.0f - 2.0f * __builtin_amdgcn_rcpf(1.0f + u);
}

__launch_bounds__(256, 4)
__global__ void espcn_fused_kernel(const float* __restrict__ x,
                                   const int* __restrict__ ci,
                                   const float* __restrict__ b1,
                                   const float* __restrict__ b2,
                                   const float* __restrict__ b3,
                                   float* __restrict__ out) {
    // LDS pool with liveness-based aliasing (31040 B):
    //   [0,1088):      xs float[16][17]           live phase 0 -> 0.5
    //   [1088,12608):  imc 144x80B                live 0.5 -> 1
    //                  h2b 100x64B (aliased)      live 2 -> 3
    //   [12608,31040): h1s 144x128B               live 1 -> 2
    //                  outT 24x28 f32 (aliased)   live 3 -> 4
    __shared__ __align__(16) char ldsp[31040];
    float (*xs)[17]   = (float(*)[17])ldsp;
    char* imc         = ldsp + 1088;
    char* h2b         = ldsp + 1088;
    char* h1s         = ldsp + 12608;
    float (*outT)[28] = (float(*)[28])(ldsp + 12608);

    const int tx = blockIdx.x, ty = blockIdx.y, b = blockIdx.z;
    const int R0 = ty * 8, C0 = tx * 8;
    int e = ci[b];
    e = __builtin_amdgcn_readfirstlane(e);                  // force SGPR: scalar weight loads
    const int t = threadIdx.x;
    const int lane = t & 63, wave = t >> 6;
    const int g = lane >> 4, r16 = lane & 15;

    // ---- phase 0: stage x patch rows [R0-4, R0+12), cols [C0-4, C0+12) ----
    {
        int i = t >> 4, j = t & 15;
        int gy = R0 - 4 + i, gx = C0 - 4 + j;
        float v = 0.f;
        if ((unsigned)gy < (unsigned)HW && (unsigned)gx < (unsigned)HW)
            v = x[(b * HW + gy) * HW + gx];
        xs[i][j] = v;
    }
    __syncthreads();

    // ---- phase 0.5: build im2col: 144 px x 16 tap-pairs (u32 writes) ----
    {
        #pragma unroll
        for (int q = 0; q < 9; ++q) {
            int idx = q * 256 + t;             // [0, 2304)
            int p = idx >> 4, w = idx & 15;
            int i = p / 12, j = p - i * 12;
            int tap0 = 2 * w, tap1 = 2 * w + 1;
            unsigned short lo = 0, hi = 0;
            if (tap0 < 25) lo = f2bf(xs[i + tap0 / 5][j + tap0 % 5]);
            if (tap1 < 25) hi = f2bf(xs[i + tap1 / 5][j + tap1 % 5]);
            *(unsigned*)(imc + p * 80 + w * 4) = (unsigned)lo | ((unsigned)hi << 16);
        }
    }
    __syncthreads();

    // ---- phase 1: conv1 as MFMA, SWAPPED: M=oc(64, tile=wave), N=pixel(144), K=32 ----
    // D: col(lane)=pixel, rows=4 consecutive oc per thread -> packed b64 stores.
    {
        const unsigned short* w1e = g_w1b + e * C1 * 32;
        bf16x8s W = *(const bf16x8s*)(w1e + (wave * 16 + r16) * 32 + g * 8);
        const int oc0 = wave * 16 + g * 4;       // this thread's 4 D-rows (oc)
        f32x4 bias4 = *(const f32x4*)(b1 + e * C1 + oc0);
        // p = mt*16 + r16 -> p&7 = r16&7 (mt-invariant): swizzle hoists out of loop.
        const int h1base = (r16 << 7) | ((wave * 32 + g * 8) ^ ((r16 & 7) << 4));
        const int imcbase = r16 * 80 + g * 16;
        #pragma unroll
        for (int mt = 0; mt < 9; ++mt) {
            bf16x8s I = *(const bf16x8s*)(imc + imcbase + mt * 1280);
            f32x4 acc = {0.f, 0.f, 0.f, 0.f};
            acc = __builtin_amdgcn_mfma_f32_16x16x32_bf16(W, I, acc, 0, 0, 0);
            int p = mt * 16 + r16;               // pixel this thread's 4 oc belong to
            int r = p / 12, jj = p - r * 12;
            int gy = R0 - 2 + r, gx = C0 - 2 + jj;
            bool in = ((unsigned)gy < (unsigned)HW) && ((unsigned)gx < (unsigned)HW);
            u16x4 hv;
            #pragma unroll
            for (int q = 0; q < 4; ++q)
                hv[q] = f2bf(in ? fast_tanh(acc[q] + bias4[q]) : 0.f);
            *(u16x4*)(h1s + h1base + mt * 2048) = hv;    // ds_write_b64, imm offset
        }
    }
    __syncthreads();

    // ---- phase 2: conv2 as MFMA, SWAPPED: M=oc(32, 2 tiles), N=pixel(128 pad), K=576 ----
    {
        const unsigned short* w2e = g_w2b + e * 9 * C2 * C1;
        int ps0 = wave * 32 + r16;       if (ps0 > 99) ps0 = 99;
        int ps1 = wave * 32 + 16 + r16;  if (ps1 > 99) ps1 = 99;
        const int ab0 = (ps0 / 10) * 12 + (ps0 % 10);
        const int ab1 = (ps1 / 10) * 12 + (ps1 % 10);
        // Hoisted swizzled row bases: off = rb[koff] ^ icoff2 (icoff2 = per-s constant).
        // Valid because (r<<7), (r&7)<<4 and icoff2 occupy disjoint/low bit fields:
        // ((r<<7)+ic2)^((r&7)<<4) == ((r<<7)|((r&7)<<4)) ^ ic2.
        int rb0[9], rb1[9];
        #pragma unroll
        for (int k = 0; k < 9; ++k) {
            int d = (k / 3) * 12 + (k % 3);
            int r0 = ab0 + d, r1 = ab1 + d;
            rb0[k] = (r0 << 7) | ((r0 & 7) << 4);
            rb1[k] = (r1 << 7) | ((r1 & 7) << 4);
        }
        f32x4 acc00 = {0.f, 0.f, 0.f, 0.f}, acc01 = {0.f, 0.f, 0.f, 0.f};
        f32x4 acc10 = {0.f, 0.f, 0.f, 0.f}, acc11 = {0.f, 0.f, 0.f, 0.f};
        const int laneB = (r16 * C1 + g * 8);          // weight A-frag: row=oc=r16
        #pragma unroll
        for (int s = 0; s < 18; ++s) {
            const int koff = s >> 1;
            const int icoff2 = ((s & 1) * 32 + g * 8) * 2;   // bits 4-6; g*16 part uniform per thread
            int o0 = rb0[koff] ^ icoff2;
            int o1 = rb1[koff] ^ icoff2;
            bf16x8s A0 = *(const bf16x8s*)(h1s + o0);   // h1 pixels (B-operand)
            bf16x8s A1 = *(const bf16x8s*)(h1s + o1);
            const unsigned short* wp = w2e + koff * C2 * C1 + (s & 1) * 32;
            bf16x8s B0 = *(const bf16x8s*)(wp + laneB);              // oc tile 0 (A-operand)
            bf16x8s B1 = *(const bf16x8s*)(wp + 16 * C1 + laneB);    // oc tile 1
            acc00 = __builtin_amdgcn_mfma_f32_16x16x32_bf16(B0, A0, acc00, 0, 0, 0);
            acc01 = __builtin_amdgcn_mfma_f32_16x16x32_bf16(B1, A0, acc01, 0, 0, 0);
            acc10 = __builtin_amdgcn_mfma_f32_16x16x32_bf16(B0, A1, acc10, 0, 0, 0);
            acc11 = __builtin_amdgcn_mfma_f32_16x16x32_bf16(B1, A1, acc11, 0, 0, 0);
        }
        // D: col=pixel (r16), rows=4 consecutive oc -> packed b64 stores per oc-tile.
        const float* b2e = b2 + e * C2;
        f32x4 bias0 = *(const f32x4*)(b2e + g * 4);
        f32x4 bias1 = *(const f32x4*)(b2e + 16 + g * 4);
        #pragma unroll
        for (int mm = 0; mm < 2; ++mm) {
            f32x4 a0 = mm ? acc10 : acc00;       // oc tile 0
            f32x4 a1 = mm ? acc11 : acc01;       // oc tile 1
            int pd = wave * 32 + mm * 16 + r16;
            if (pd < 100) {
                int y = pd / 10, xq2 = pd - y * 10;
                int gy = R0 - 1 + y, gx = C0 - 1 + xq2;
                bool in = ((unsigned)gy < (unsigned)HW) && ((unsigned)gx < (unsigned)HW);
                u16x4 h0, h1;
                #pragma unroll
                for (int q = 0; q < 4; ++q) {
                    h0[q] = f2bf(in ? fast_tanh(a0[q] + bias0[q]) : 0.f);
                    h1[q] = f2bf(in ? fast_tanh(a1[q] + bias1[q]) : 0.f);
                }
                int swz = (pd & 3) << 4;
                *(u16x4*)(h2b + (pd << 6) + ((g * 8) ^ swz)) = h0;
                *(u16x4*)(h2b + (pd << 6) + ((32 + g * 8) ^ swz)) = h1;
            }
        }
    }
    __syncthreads();

    // ---- phase 3: conv3 (3x3, 32->9 pad 16) as bf16 MFMA -> LDS out tile ----
    // M = 64 output pixels (4 tiles, one per wave), N = 16 (9 valid), K = 288 (9 steps).
    {
        const unsigned short* w3e = g_w3b + e * 9 * 16 * 32;
        const int pxA = wave * 16 + r16;            // A-row pixel
        const int oyA = pxA >> 3, oxA = pxA & 7;
        const int pbase = oyA * 10 + oxA;
        f32x4 acc = {0.f, 0.f, 0.f, 0.f};
        #pragma unroll
        for (int s = 0; s < 9; ++s) {
            int p = pbase + (s / 3) * 10 + (s % 3);
            int offA = (p << 6) | ((g * 16) ^ ((p & 3) << 4));
            bf16x8s A = *(const bf16x8s*)(h2b + offA);
            bf16x8s B = *(const bf16x8s*)(w3e + (s * 16 + r16) * 32 + g * 8);
            acc = __builtin_amdgcn_mfma_f32_16x16x32_bf16(A, B, acc, 0, 0, 0);
        }
        // D: row (pixel-in-tile) = g*4+q, col (oc) = r16.  Stage into LDS tile.
        if (r16 < C3) {
            float bias = b3[e * C3 + r16];
            #pragma unroll
            for (int q = 0; q < 4; ++q) {
                int pxd = wave * 16 + g * 4 + q;
                int oyd = pxd >> 3, oxd = pxd & 7;
                outT[oyd * 3 + r16 / 3][oxd * 3 + r16 % 3] = acc[q] + bias;
            }
        }
    }
    __syncthreads();

    // ---- phase 4: coalesced output write: 24 rows x 6 float4 (96 B/row) ----
    if (t < 144) {
        int row = t / 6, c4 = t - row * 6;
        f32x4 v = *(const f32x4*)&outT[row][c4 * 4];
        int gr = R0 * 3 + row;              // 24*ty + row
        int gc = C0 * 3 + c4 * 4;           // 24*tx + 4*c4
        *(f32x4*)&out[(b * OUT_HW + gr) * OUT_HW + gc] = v;
    }
}

extern "C" void kernel_launch(void* const* d_in, const int* in_sizes, int n_in,
                              void* d_out, int out_size, void* d_ws, size_t ws_size,
                              hipStream_t stream) {
    const float* x  = (const float*)d_in[0];
    const int*   ci = (const int*)  d_in[1];
    const float* w1 = (const float*)d_in[2];
    const float* b1 = (const float*)d_in[3];
    const float* w2 = (const float*)d_in[4];
    const float* b2 = (const float*)d_in[5];
    const float* w3 = (const float*)d_in[6];
    const float* b3 = (const float*)d_in[7];
    float* out = (float*)d_out;

    {
        const int total = NE * C2 * C1 * 9 + NE * C1 * 32 + NE * 9 * 16 * 32;
        repack_weights_kernel<<<(total + 255) / 256, 256, 0, stream>>>(w1, w2, w3);
    }
    {
        dim3 grid(HW / 8, HW / 8, 32);
        espcn_fused_kernel<<<grid, 256, 0, stream>>>(x, ci, b1, b2, b3, out);
    }
}

// Round 11
// 168.720 us; speedup vs baseline: 1.4660x; 1.4634x over previous
//
#include <hip/hip_runtime.h>

#define NE 8
#define HW 128
#define OUT_HW 384
#define C1 64
#define C2 32
#define C3 9

typedef __attribute__((ext_vector_type(4))) float f32x4;
typedef __attribute__((ext_vector_type(8))) short bf16x8s;
typedef __attribute__((ext_vector_type(4))) unsigned short u16x4;

// Prepacked conv1 weights, bf16: [e][oc=64][tap=32 (25 valid, rest 0)]
__device__ __align__(16) unsigned short g_w1b[NE * C1 * 32];
// Prepacked conv2 weights, bf16: [e][koff(ky*3+kx)][oc=32][ic=64]
__device__ __align__(16) unsigned short g_w2b[NE * 9 * C2 * C1];
// Prepacked conv3 weights, bf16: [e][koff][oc=16 (9 valid)][ic=32]
__device__ __align__(16) unsigned short g_w3b[NE * 9 * 16 * 32];

__device__ __forceinline__ unsigned short f2bf(float f) {
    unsigned u = __builtin_bit_cast(unsigned, f);
    u += 0x7fffu + ((u >> 16) & 1u);          // round-nearest-even
    return (unsigned short)(u >> 16);
}

__global__ void repack_weights_kernel(const float* __restrict__ w1,
                                      const float* __restrict__ w2,
                                      const float* __restrict__ w3) {
    int i = blockIdx.x * 256 + threadIdx.x;
    const int n2 = NE * C2 * C1 * 9;          // 36864
    const int n1 = NE * C1 * 32;              // 16384
    const int n3 = NE * 9 * 16 * 32;          // 36864
    if (i < n2) {
        // source: [e][oc][ic][ky][kx] -> dest [e][koff][oc][ic]
        int e = i / (C2 * C1 * 9);
        int r = i - e * (C2 * C1 * 9);
        int oc = r / (C1 * 9); r -= oc * (C1 * 9);
        int ic = r / 9;
        int koff = r - ic * 9;
        g_w2b[((e * 9 + koff) * C2 + oc) * C1 + ic] = f2bf(w2[i]);
    } else if (i < n2 + n1) {
        int j = i - n2;                        // [e][oc][tap]
        int tap = j & 31;
        int eoc = j >> 5;                      // e*64+oc
        float v = (tap < 25) ? w1[eoc * 25 + tap] : 0.f;
        g_w1b[j] = f2bf(v);
    } else if (i < n2 + n1 + n3) {
        int j = i - n2 - n1;
        int e = j / (9 * 16 * 32);
        int r = j - e * (9 * 16 * 32);
        int koff = r / 512; r -= koff * 512;
        int oc = r / 32;
        int ic = r - oc * 32;
        float v = 0.f;
        if (oc < C3) v = w3[((e * C3 + oc) * 32 + ic) * 9 + koff];
        g_w3b[((e * 9 + koff) * 16 + oc) * 32 + ic] = f2bf(v);
    }
}

// tanh(x) = 1 - 2/(1+e^{2x}); inf-safe both directions.  5 VALU (2 trans).
__device__ __forceinline__ float fast_tanh(float x) {
    float u = __builtin_amdgcn_exp2f(x * 2.88539008f);   // e^{2x}
    return 1.0f - 2.0f * __builtin_amdgcn_rcpf(1.0f + u);
}

__launch_bounds__(512, 4)
__global__ void espcn_fused_kernel(const float* __restrict__ x,
                                   const int* __restrict__ ci,
                                   const float* __restrict__ b1,
                                   const float* __restrict__ b2,
                                   const float* __restrict__ b3,
                                   float* __restrict__ out) {
    // LDS pool, liveness-aliased (79200 B -> 2 blocks/CU, 16 waves/CU):
    //   [0,2400):      xs float[24][25]            live 0 -> 0.5
    //   [2400,28000):  imc 400x64B                 live 0.5 -> 1
    //                  h2b 324x64B (aliased)       live 2 -> 3
    //   [28000,79200): h1s 400x128B                live 1 -> 2
    //                  outT 48x52 f32 (aliased)    live 3 -> 4
    __shared__ __align__(16) char ldsp[79200];
    float (*xs)[25]   = (float(*)[25])ldsp;
    char* imc         = ldsp + 2400;
    char* h2b         = ldsp + 2400;
    char* h1s         = ldsp + 28000;
    float (*outT)[52] = (float(*)[52])(ldsp + 28000);

    const int tx = blockIdx.x, ty = blockIdx.y, b = blockIdx.z;
    const int R0 = ty * 16, C0 = tx * 16;
    int e = ci[b];
    e = __builtin_amdgcn_readfirstlane(e);
    const int t = threadIdx.x;                 // 0..511
    const int lane = t & 63, wave = t >> 6;    // 8 waves
    const int g = lane >> 4, r16 = lane & 15;

    // ---- phase 0: stage x patch rows [R0-4, R0+20), cols [C0-4, C0+20) ----
    #pragma unroll
    for (int it = 0; it < 2; ++it) {
        int idx = it * 512 + t;
        if (idx < 576) {
            int ii = idx / 24, jj = idx - ii * 24;
            int gy = R0 - 4 + ii, gx = C0 - 4 + jj;
            float v = 0.f;
            if ((unsigned)gy < (unsigned)HW && (unsigned)gx < (unsigned)HW)
                v = x[(b * HW + gy) * HW + gx];
            xs[ii][jj] = v;
        }
    }
    __syncthreads();

    // ---- phase 0.5: im2col 400 px x 16 tap-pairs.  w = t&15 is loop-invariant. ----
    {
        const int w = t & 15, pr = t >> 4;      // pr 0..31
        int t0 = 2 * w;     if (t0 > 24) t0 = 24;
        int t1 = 2 * w + 1; if (t1 > 24) t1 = 24;
        const int dy0 = t0 / 5, dx0 = t0 - 5 * (t0 / 5);
        const int dy1 = t1 / 5, dx1 = t1 - 5 * (t1 / 5);
        const bool v0 = (2 * w) < 25, v1 = (2 * w + 1) < 25;
        const int swz = (w * 4) ^ ((pr & 3) << 4);   // p&3 == pr&3 (32|p-step)
        #pragma unroll
        for (int it = 0; it < 13; ++it) {
            int p = it * 32 + pr;
            if (p < 400) {
                int i = p / 20, j = p - i * 20;
                unsigned short lo = v0 ? f2bf(xs[i + dy0][j + dx0]) : (unsigned short)0;
                unsigned short hi = v1 ? f2bf(xs[i + dy1][j + dx1]) : (unsigned short)0;
                *(unsigned*)(imc + p * 64 + swz) = (unsigned)lo | ((unsigned)hi << 16);
            }
        }
    }
    __syncthreads();

    // ---- phase 1: conv1 MFMA swapped (M=oc 64: 4 tiles, N=px 400: 25 tiles, K=32) ----
    {
        const unsigned short* w1e = g_w1b + e * C1 * 32;
        const int octile = wave & 3, hi = wave >> 2;
        bf16x8s W = *(const bf16x8s*)(w1e + (octile * 16 + r16) * 32 + g * 8);
        f32x4 bias4 = *(const f32x4*)(b1 + e * C1 + octile * 16 + g * 4);
        const int imcb = r16 * 64 + ((g * 16) ^ ((r16 & 3) << 4));
        const int h1b = (r16 << 7) + ((octile * 32 + g * 8) ^ ((r16 & 7) << 4));
        #pragma unroll
        for (int k = 0; k < 13; ++k) {
            int pt = hi + 2 * k;
            if (pt < 25) {
                bf16x8s I = *(const bf16x8s*)(imc + pt * 1024 + imcb);
                f32x4 acc = {0.f, 0.f, 0.f, 0.f};
                acc = __builtin_amdgcn_mfma_f32_16x16x32_bf16(W, I, acc, 0, 0, 0);
                int p = pt * 16 + r16;
                int i = p / 20, j = p - i * 20;
                int gy = R0 - 2 + i, gx = C0 - 2 + j;
                bool in = ((unsigned)gy < (unsigned)HW) && ((unsigned)gx < (unsigned)HW);
                u16x4 hv;
                #pragma unroll
                for (int q = 0; q < 4; ++q)
                    hv[q] = f2bf(in ? fast_tanh(acc[q] + bias4[q]) : 0.f);
                *(u16x4*)(h1s + h1b + pt * 2048) = hv;
            }
        }
    }
    __syncthreads();

    // ---- phase 2: conv2 MFMA swapped (M=oc 32: 2 tiles, N=px 324: 21 tiles, K=576) ----
    // 3 px-tile slots per wave: {w, w+8, w+16}; slot 2 dup-clamped for waves 5-7.
    {
        const unsigned short* w2e = g_w2b + e * 9 * C2 * C1;
        const bool has2 = (wave + 16) < 21;
        const int pt0 = wave, pt1 = wave + 8, pt2 = has2 ? wave + 16 : wave;
        int ab[3];
        {
            int pts[3] = {pt0, pt1, pt2};
            #pragma unroll
            for (int s3 = 0; s3 < 3; ++s3) {
                int px = pts[s3] * 16 + r16; if (px > 323) px = 323;
                int r = px / 18, c = px - r * 18;
                ab[s3] = r * 20 + c;
            }
        }
        // Hoisted swizzled row bases rb[slot][koff]
        int rb[3][9];
        #pragma unroll
        for (int s3 = 0; s3 < 3; ++s3)
            #pragma unroll
            for (int k = 0; k < 9; ++k) {
                int ap = ab[s3] + (k / 3) * 20 + (k % 3);
                rb[s3][k] = (ap << 7) | ((ap & 7) << 4);
            }
        f32x4 a00 = {0.f,0.f,0.f,0.f}, a01 = {0.f,0.f,0.f,0.f};
        f32x4 a10 = {0.f,0.f,0.f,0.f}, a11 = {0.f,0.f,0.f,0.f};
        f32x4 a20 = {0.f,0.f,0.f,0.f}, a21 = {0.f,0.f,0.f,0.f};
        const int laneB = r16 * C1 + g * 8;
        const int icb = g * 16;
        #pragma unroll
        for (int s = 0; s < 18; ++s) {
            const int koff = s >> 1;
            const int ic = (s & 1) * 64 + icb;
            const unsigned short* wp = w2e + koff * (C2 * C1) + (s & 1) * 32;
            bf16x8s B0 = *(const bf16x8s*)(wp + laneB);
            bf16x8s B1 = *(const bf16x8s*)(wp + laneB + 16 * C1);
            bf16x8s A0 = *(const bf16x8s*)(h1s + (rb[0][koff] ^ ic));
            bf16x8s A1 = *(const bf16x8s*)(h1s + (rb[1][koff] ^ ic));
            a00 = __builtin_amdgcn_mfma_f32_16x16x32_bf16(B0, A0, a00, 0, 0, 0);
            a01 = __builtin_amdgcn_mfma_f32_16x16x32_bf16(B1, A0, a01, 0, 0, 0);
            a10 = __builtin_amdgcn_mfma_f32_16x16x32_bf16(B0, A1, a10, 0, 0, 0);
            a11 = __builtin_amdgcn_mfma_f32_16x16x32_bf16(B1, A1, a11, 0, 0, 0);
            if (has2) {
                bf16x8s A2 = *(const bf16x8s*)(h1s + (rb[2][koff] ^ ic));
                a20 = __builtin_amdgcn_mfma_f32_16x16x32_bf16(B0, A2, a20, 0, 0, 0);
                a21 = __builtin_amdgcn_mfma_f32_16x16x32_bf16(B1, A2, a21, 0, 0, 0);
            }
        }
        // epilogue: D col=px(r16), rows=4 consecutive oc -> packed b64 per oc-tile
        const float* b2e = b2 + e * C2;
        f32x4 bias0 = *(const f32x4*)(b2e + g * 4);
        f32x4 bias1 = *(const f32x4*)(b2e + 16 + g * 4);
        const int wb0 = (g * 8) ^ ((r16 & 3) << 4);        // px&3 == r16&3
        const int wb1 = (32 + g * 8) ^ ((r16 & 3) << 4);
        #pragma unroll
        for (int s3 = 0; s3 < 3; ++s3) {
            int pt = (s3 == 0) ? pt0 : (s3 == 1) ? pt1 : pt2;
            f32x4 aa0 = (s3 == 0) ? a00 : (s3 == 1) ? a10 : a20;
            f32x4 aa1 = (s3 == 0) ? a01 : (s3 == 1) ? a11 : a21;
            int px = pt * 16 + r16;
            bool wvalid = (px < 324) && (s3 != 2 || has2);
            if (wvalid) {
                int y = px / 18, xx = px - y * 18;
                int gy = R0 - 1 + y, gx = C0 - 1 + xx;
                bool in = ((unsigned)gy < (unsigned)HW) && ((unsigned)gx < (unsigned)HW);
                u16x4 h0, h1;
                #pragma unroll
                for (int q = 0; q < 4; ++q) {
                    h0[q] = f2bf(in ? fast_tanh(aa0[q] + bias0[q]) : 0.f);
                    h1[q] = f2bf(in ? fast_tanh(aa1[q] + bias1[q]) : 0.f);
                }
                *(u16x4*)(h2b + (px << 6) + wb0) = h0;
                *(u16x4*)(h2b + (px << 6) + wb1) = h1;
            }
        }
    }
    __syncthreads();

    // ---- phase 3: conv3 MFMA (M=px 256: 16 tiles, 2/wave; N=16 (9 oc); K=288) ----
    {
        const unsigned short* w3e = g_w3b + e * 9 * 16 * 32;
        const int px0 = (wave * 2) * 16 + r16, px1 = (wave * 2 + 1) * 16 + r16;
        const int pb0 = (px0 >> 4) * 18 + (px0 & 15);
        const int pb1 = (px1 >> 4) * 18 + (px1 & 15);
        f32x4 acc0 = {0.f,0.f,0.f,0.f}, acc1 = {0.f,0.f,0.f,0.f};
        #pragma unroll
        for (int s = 0; s < 9; ++s) {
            int d = (s / 3) * 18 + (s % 3);
            int p0 = pb0 + d, p1 = pb1 + d;
            bf16x8s A0 = *(const bf16x8s*)(h2b + ((p0 << 6) | ((g * 16) ^ ((p0 & 3) << 4))));
            bf16x8s A1 = *(const bf16x8s*)(h2b + ((p1 << 6) | ((g * 16) ^ ((p1 & 3) << 4))));
            bf16x8s B = *(const bf16x8s*)(w3e + (s * 16 + r16) * 32 + g * 8);
            acc0 = __builtin_amdgcn_mfma_f32_16x16x32_bf16(A0, B, acc0, 0, 0, 0);
            acc1 = __builtin_amdgcn_mfma_f32_16x16x32_bf16(A1, B, acc1, 0, 0, 0);
        }
        if (r16 < C3) {
            float bias = b3[e * C3 + r16];
            const int ocr = r16 / 3, occ = r16 % 3;
            #pragma unroll
            for (int m = 0; m < 2; ++m) {
                f32x4 a = m ? acc1 : acc0;
                #pragma unroll
                for (int q = 0; q < 4; ++q) {
                    int pxd = (wave * 2 + m) * 16 + g * 4 + q;
                    int oy = pxd >> 4, ox = pxd & 15;
                    outT[oy * 3 + ocr][ox * 3 + occ] = a[q] + bias;
                }
            }
        }
    }
    __syncthreads();

    // ---- phase 4: coalesced output write: 48 rows x 12 float4 (192 B/row) ----
    #pragma unroll
    for (int it = 0; it < 2; ++it) {
        int idx = it * 512 + t;
        if (idx < 576) {
            int row = idx / 12, c4 = idx - row * 12;
            f32x4 v = *(const f32x4*)&outT[row][c4 * 4];
            *(f32x4*)&out[(b * OUT_HW + 48 * ty + row) * OUT_HW + 48 * tx + c4 * 4] = v;
        }
    }
}

extern "C" void kernel_launch(void* const* d_in, const int* in_sizes, int n_in,
                              void* d_out, int out_size, void* d_ws, size_t ws_size,
                              hipStream_t stream) {
    const float* x  = (const float*)d_in[0];
    const int*   ci = (const int*)  d_in[1];
    const float* w1 = (const float*)d_in[2];
    const float* b1 = (const float*)d_in[3];
    const float* w2 = (const float*)d_in[4];
    const float* b2 = (const float*)d_in[5];
    const float* w3 = (const float*)d_in[6];
    const float* b3 = (const float*)d_in[7];
    float* out = (float*)d_out;

    {
        const int total = NE * C2 * C1 * 9 + NE * C1 * 32 + NE * 9 * 16 * 32;
        repack_weights_kernel<<<(total + 255) / 256, 256, 0, stream>>>(w1, w2, w3);
    }
    {
        dim3 grid(HW / 16, HW / 16, 32);
        espcn_fused_kernel<<<grid, 512, 0, stream>>>(x, ci, b1, b2, b3, out);
    }
}

// Round 14
// 164.870 us; speedup vs baseline: 1.5003x; 1.0234x over previous
//
#include <hip/hip_runtime.h>

#define NE 8
#define HW 128
#define OUT_HW 384
#define C1 64
#define C2 32
#define C3 9

typedef __attribute__((ext_vector_type(4))) float f32x4;
typedef __attribute__((ext_vector_type(8))) short bf16x8s;
typedef __attribute__((ext_vector_type(2))) unsigned u32x2;

// Prepacked conv1 weights, bf16: [e][oc=64][tap=32 (25 valid, rest 0)]
__device__ __align__(16) unsigned short g_w1b[NE * C1 * 32];
// Prepacked conv2 weights, bf16: [e][koff(ky*3+kx)][oc=32][ic=64]
__device__ __align__(16) unsigned short g_w2b[NE * 9 * C2 * C1];
// Prepacked conv3 weights, bf16: [e][koff][oc=16 (9 valid)][ic=32]
__device__ __align__(16) unsigned short g_w3b[NE * 9 * 16 * 32];

__device__ __forceinline__ unsigned short f2bf(float f) {
    unsigned u = __builtin_bit_cast(unsigned, f);
    u += 0x7fffu + ((u >> 16) & 1u);          // round-nearest-even
    return (unsigned short)(u >> 16);
}

// Packed f32x2 -> bf16x2 (RNE), 1 VALU inst.  No builtin on gfx950 (T12/m240).
__device__ __forceinline__ unsigned cvt_pk_bf16(float lo, float hi) {
    unsigned r;
    asm("v_cvt_pk_bf16_f32 %0, %1, %2" : "=v"(r) : "v"(lo), "v"(hi));
    return r;
}

__global__ void repack_weights_kernel(const float* __restrict__ w1,
                                      const float* __restrict__ w2,
                                      const float* __restrict__ w3) {
    int i = blockIdx.x * 256 + threadIdx.x;
    const int n2 = NE * C2 * C1 * 9;          // 36864
    const int n1 = NE * C1 * 32;              // 16384
    const int n3 = NE * 9 * 16 * 32;          // 36864
    if (i < n2) {
        // source: [e][oc][ic][ky][kx] -> dest [e][koff][oc][ic]
        int e = i / (C2 * C1 * 9);
        int r = i - e * (C2 * C1 * 9);
        int oc = r / (C1 * 9); r -= oc * (C1 * 9);
        int ic = r / 9;
        int koff = r - ic * 9;
        g_w2b[((e * 9 + koff) * C2 + oc) * C1 + ic] = f2bf(w2[i]);
    } else if (i < n2 + n1) {
        int j = i - n2;                        // [e][oc][tap]
        int tap = j & 31;
        int eoc = j >> 5;                      // e*64+oc
        float v = (tap < 25) ? w1[eoc * 25 + tap] : 0.f;
        g_w1b[j] = f2bf(v);
    } else if (i < n2 + n1 + n3) {
        int j = i - n2 - n1;
        int e = j / (9 * 16 * 32);
        int r = j - e * (9 * 16 * 32);
        int koff = r / 512; r -= koff * 512;
        int oc = r / 32;
        int ic = r - oc * 32;
        float v = 0.f;
        if (oc < C3) v = w3[((e * C3 + oc) * 32 + ic) * 9 + koff];
        g_w3b[((e * 9 + koff) * 16 + oc) * 32 + ic] = f2bf(v);
    }
}

// tanh(x) = 1 - 2/(1+e^{2x}); inf-safe both directions.  5 VALU (2 trans).
__device__ __forceinline__ float fast_tanh(float x) {
    float u = __builtin_amdgcn_exp2f(x * 2.88539008f);   // e^{2x}
    return 1.0f - 2.0f * __builtin_amdgcn_rcpf(1.0f + u);
}

__launch_bounds__(512, 4)
__global__ void espcn_fused_kernel(const float* __restrict__ x,
                                   const int* __restrict__ ci,
                                   const float* __restrict__ b1,
                                   const float* __restrict__ b2,
                                   const float* __restrict__ b3,
                                   float* __restrict__ out) {
    // LDS pool, liveness-aliased (79200 B -> 2 blocks/CU, 16 waves/CU):
    //   [0,2400):      xs float[24][25]            live 0 -> 0.5
    //   [2400,28000):  imc 400x64B                 live 0.5 -> 1
    //                  h2b 324x64B (aliased)       live 2 -> 3
    //   [28000,79200): h1s 400x128B                live 1 -> 2
    //                  outT 48x52 f32 (aliased)    live 3 -> 4
    __shared__ __align__(16) char ldsp[79200];
    float (*xs)[25]   = (float(*)[25])ldsp;
    char* imc         = ldsp + 2400;
    char* h2b         = ldsp + 2400;
    char* h1s         = ldsp + 28000;
    float (*outT)[52] = (float(*)[52])(ldsp + 28000);

    const int tx = blockIdx.x, ty = blockIdx.y, b = blockIdx.z;
    const int R0 = ty * 16, C0 = tx * 16;
    // Block-uniform (SGPR) interior predicate: all halos in-image -> skip bounds.
    const bool interior = (tx >= 1) && (tx <= 6) && (ty >= 1) && (ty <= 6);
    int e = ci[b];
    e = __builtin_amdgcn_readfirstlane(e);
    const int t = threadIdx.x;                 // 0..511
    const int lane = t & 63, wave = t >> 6;    // 8 waves
    const int g = lane >> 4, r16 = lane & 15;

    // ---- phase 0: stage x patch rows [R0-4, R0+20), cols [C0-4, C0+20) ----
    #pragma unroll
    for (int it = 0; it < 2; ++it) {
        int idx = it * 512 + t;
        if (idx < 576) {
            int ii = idx / 24, jj = idx - ii * 24;
            int gy = R0 - 4 + ii, gx = C0 - 4 + jj;
            float v = 0.f;
            if (interior || ((unsigned)gy < (unsigned)HW && (unsigned)gx < (unsigned)HW))
                v = x[(b * HW + gy) * HW + gx];
            xs[ii][jj] = v;
        }
    }
    __syncthreads();

    // ---- phase 0.5: im2col 400 px x 16 tap-pairs.  w = t&15 is loop-invariant. ----
    {
        const int w = t & 15, pr = t >> 4;      // pr 0..31
        int t0 = 2 * w;     if (t0 > 24) t0 = 24;
        int t1 = 2 * w + 1; if (t1 > 24) t1 = 24;
        const int dy0 = t0 / 5, dx0 = t0 - 5 * (t0 / 5);
        const int dy1 = t1 / 5, dx1 = t1 - 5 * (t1 / 5);
        const bool v0 = (2 * w) < 25, v1 = (2 * w + 1) < 25;
        const int swz = (w * 4) ^ ((pr & 3) << 4);   // p&3 == pr&3 (32|p-step)
        #pragma unroll
        for (int it = 0; it < 13; ++it) {
            int p = it * 32 + pr;
            if (p < 400) {
                int i = p / 20, j = p - i * 20;
                float f0 = v0 ? xs[i + dy0][j + dx0] : 0.f;
                float f1 = v1 ? xs[i + dy1][j + dx1] : 0.f;
                *(unsigned*)(imc + p * 64 + swz) = cvt_pk_bf16(f0, f1);
            }
        }
    }
    __syncthreads();

    // ---- phase 1: conv1 MFMA swapped (M=oc 64: 4 tiles, N=px 400: 25 tiles, K=32) ----
    {
        const unsigned short* w1e = g_w1b + e * C1 * 32;
        const int octile = wave & 3, hi = wave >> 2;
        bf16x8s W = *(const bf16x8s*)(w1e + (octile * 16 + r16) * 32 + g * 8);
        f32x4 bias4 = *(const f32x4*)(b1 + e * C1 + octile * 16 + g * 4);
        const int imcb = r16 * 64 + ((g * 16) ^ ((r16 & 3) << 4));
        const int h1b = (r16 << 7) + ((octile * 32 + g * 8) ^ ((r16 & 7) << 4));
        #pragma unroll
        for (int k = 0; k < 13; ++k) {
            int pt = hi + 2 * k;
            if (pt < 25) {
                bf16x8s I = *(const bf16x8s*)(imc + pt * 1024 + imcb);
                f32x4 acc = {0.f, 0.f, 0.f, 0.f};
                acc = __builtin_amdgcn_mfma_f32_16x16x32_bf16(W, I, acc, 0, 0, 0);
                float s0 = fast_tanh(acc[0] + bias4[0]);
                float s1 = fast_tanh(acc[1] + bias4[1]);
                float s2 = fast_tanh(acc[2] + bias4[2]);
                float s3 = fast_tanh(acc[3] + bias4[3]);
                if (!interior) {
                    int p = pt * 16 + r16;
                    int i = p / 20, j = p - i * 20;
                    int gy = R0 - 2 + i, gx = C0 - 2 + j;
                    bool in = ((unsigned)gy < (unsigned)HW) && ((unsigned)gx < (unsigned)HW);
                    if (!in) { s0 = 0.f; s1 = 0.f; s2 = 0.f; s3 = 0.f; }
                }
                u32x2 hv = { cvt_pk_bf16(s0, s1), cvt_pk_bf16(s2, s3) };
                *(u32x2*)(h1s + h1b + pt * 2048) = hv;
            }
        }
    }
    __syncthreads();

    // ---- phase 2: conv2 MFMA swapped (M=oc 32: 2 tiles, N=px 324: 21 tiles, K=576) ----
    // 3 px-tile slots per wave: {w, w+8, w+16}; slot 2 dup-clamped for waves 5-7.
    {
        const unsigned short* w2e = g_w2b + e * 9 * C2 * C1;
        const bool has2 = (wave + 16) < 21;
        const int pt0 = wave, pt1 = wave + 8, pt2 = has2 ? wave + 16 : wave;
        int ab[3];
        {
            int pts[3] = {pt0, pt1, pt2};
            #pragma unroll
            for (int s3 = 0; s3 < 3; ++s3) {
                int px = pts[s3] * 16 + r16; if (px > 323) px = 323;
                int r = px / 18, c = px - r * 18;
                ab[s3] = r * 20 + c;
            }
        }
        // Hoisted swizzled row bases rb[slot][koff]
        int rb[3][9];
        #pragma unroll
        for (int s3 = 0; s3 < 3; ++s3)
            #pragma unroll
            for (int k = 0; k < 9; ++k) {
                int ap = ab[s3] + (k / 3) * 20 + (k % 3);
                rb[s3][k] = (ap << 7) | ((ap & 7) << 4);
            }
        f32x4 a00 = {0.f,0.f,0.f,0.f}, a01 = {0.f,0.f,0.f,0.f};
        f32x4 a10 = {0.f,0.f,0.f,0.f}, a11 = {0.f,0.f,0.f,0.f};
        f32x4 a20 = {0.f,0.f,0.f,0.f}, a21 = {0.f,0.f,0.f,0.f};
        const int laneB = r16 * C1 + g * 8;
        const int icb = g * 16;
        #pragma unroll
        for (int s = 0; s < 18; ++s) {
            const int koff = s >> 1;
            const int ic = (s & 1) * 64 + icb;
            const unsigned short* wp = w2e + koff * (C2 * C1) + (s & 1) * 32;
            bf16x8s B0 = *(const bf16x8s*)(wp + laneB);
            bf16x8s B1 = *(const bf16x8s*)(wp + laneB + 16 * C1);
            bf16x8s A0 = *(const bf16x8s*)(h1s + (rb[0][koff] ^ ic));
            bf16x8s A1 = *(const bf16x8s*)(h1s + (rb[1][koff] ^ ic));
            a00 = __builtin_amdgcn_mfma_f32_16x16x32_bf16(B0, A0, a00, 0, 0, 0);
            a01 = __builtin_amdgcn_mfma_f32_16x16x32_bf16(B1, A0, a01, 0, 0, 0);
            a10 = __builtin_amdgcn_mfma_f32_16x16x32_bf16(B0, A1, a10, 0, 0, 0);
            a11 = __builtin_amdgcn_mfma_f32_16x16x32_bf16(B1, A1, a11, 0, 0, 0);
            if (has2) {
                bf16x8s A2 = *(const bf16x8s*)(h1s + (rb[2][koff] ^ ic));
                a20 = __builtin_amdgcn_mfma_f32_16x16x32_bf16(B0, A2, a20, 0, 0, 0);
                a21 = __builtin_amdgcn_mfma_f32_16x16x32_bf16(B1, A2, a21, 0, 0, 0);
            }
        }
        // epilogue: D col=px(r16), rows=4 consecutive oc -> packed b64 per oc-tile
        const float* b2e = b2 + e * C2;
        f32x4 bias0 = *(const f32x4*)(b2e + g * 4);
        f32x4 bias1 = *(const f32x4*)(b2e + 16 + g * 4);
        const int wb0 = (g * 8) ^ ((r16 & 3) << 4);        // px&3 == r16&3
        const int wb1 = (32 + g * 8) ^ ((r16 & 3) << 4);
        #pragma unroll
        for (int s3 = 0; s3 < 3; ++s3) {
            int pt = (s3 == 0) ? pt0 : (s3 == 1) ? pt1 : pt2;
            f32x4 aa0 = (s3 == 0) ? a00 : (s3 == 1) ? a10 : a20;
            f32x4 aa1 = (s3 == 0) ? a01 : (s3 == 1) ? a11 : a21;
            int px = pt * 16 + r16;
            bool wvalid = (px < 324) && (s3 != 2 || has2);
            if (wvalid) {
                float u0 = fast_tanh(aa0[0] + bias0[0]);
                float u1 = fast_tanh(aa0[1] + bias0[1]);
                float u2 = fast_tanh(aa0[2] + bias0[2]);
                float u3 = fast_tanh(aa0[3] + bias0[3]);
                float v0 = fast_tanh(aa1[0] + bias1[0]);
                float v1 = fast_tanh(aa1[1] + bias1[1]);
                float v2 = fast_tanh(aa1[2] + bias1[2]);
                float v3 = fast_tanh(aa1[3] + bias1[3]);
                if (!interior) {
                    int y = px / 18, xx = px - y * 18;
                    int gy = R0 - 1 + y, gx = C0 - 1 + xx;
                    bool in = ((unsigned)gy < (unsigned)HW) && ((unsigned)gx < (unsigned)HW);
                    if (!in) {
                        u0 = u1 = u2 = u3 = 0.f;
                        v0 = v1 = v2 = v3 = 0.f;
                    }
                }
                u32x2 h0 = { cvt_pk_bf16(u0, u1), cvt_pk_bf16(u2, u3) };
                u32x2 h1v = { cvt_pk_bf16(v0, v1), cvt_pk_bf16(v2, v3) };
                *(u32x2*)(h2b + (px << 6) + wb0) = h0;
                *(u32x2*)(h2b + (px << 6) + wb1) = h1v;
            }
        }
    }
    __syncthreads();

    // ---- phase 3: conv3 MFMA (M=px 256: 16 tiles, 2/wave; N=16 (9 oc); K=288) ----
    {
        const unsigned short* w3e = g_w3b + e * 9 * 16 * 32;
        const int px0 = (wave * 2) * 16 + r16, px1 = (wave * 2 + 1) * 16 + r16;
        const int pb0 = (px0 >> 4) * 18 + (px0 & 15);
        const int pb1 = (px1 >> 4) * 18 + (px1 & 15);
        f32x4 acc0 = {0.f,0.f,0.f,0.f}, acc1 = {0.f,0.f,0.f,0.f};
        #pragma unroll
        for (int s = 0; s < 9; ++s) {
            int d = (s / 3) * 18 + (s % 3);
            int p0 = pb0 + d, p1 = pb1 + d;
            bf16x8s A0 = *(const bf16x8s*)(h2b + ((p0 << 6) | ((g * 16) ^ ((p0 & 3) << 4))));
            bf16x8s A1 = *(const bf16x8s*)(h2b + ((p1 << 6) | ((g * 16) ^ ((p1 & 3) << 4))));
            bf16x8s B = *(const bf16x8s*)(w3e + (s * 16 + r16) * 32 + g * 8);
            acc0 = __builtin_amdgcn_mfma_f32_16x16x32_bf16(A0, B, acc0, 0, 0, 0);
            acc1 = __builtin_amdgcn_mfma_f32_16x16x32_bf16(A1, B, acc1, 0, 0, 0);
        }
        if (r16 < C3) {
            float bias = b3[e * C3 + r16];
            const int ocr = r16 / 3, occ = r16 % 3;
            #pragma unroll
            for (int m = 0; m < 2; ++m) {
                f32x4 a = m ? acc1 : acc0;
                #pragma unroll
                for (int q = 0; q < 4; ++q) {
                    int pxd = (wave * 2 + m) * 16 + g * 4 + q;
                    int oy = pxd >> 4, ox = pxd & 15;
                    outT[oy * 3 + ocr][ox * 3 + occ] = a[q] + bias;
                }
            }
        }
    }
    __syncthreads();

    // ---- phase 4: coalesced output write: 48 rows x 12 float4 (192 B/row) ----
    #pragma unroll
    for (int it = 0; it < 2; ++it) {
        int idx = it * 512 + t;
        if (idx < 576) {
            int row = idx / 12, c4 = idx - row * 12;
            f32x4 v = *(const f32x4*)&outT[row][c4 * 4];
            *(f32x4*)&out[(b * OUT_HW + 48 * ty + row) * OUT_HW + 48 * tx + c4 * 4] = v;
        }
    }
}

extern "C" void kernel_launch(void* const* d_in, const int* in_sizes, int n_in,
                              void* d_out, int out_size, void* d_ws, size_t ws_size,
                              hipStream_t stream) {
    const float* x  = (const float*)d_in[0];
    const int*   ci = (const int*)  d_in[1];
    const float* w1 = (const float*)d_in[2];
    const float* b1 = (const float*)d_in[3];
    const float* w2 = (const float*)d_in[4];
    const float* b2 = (const float*)d_in[5];
    const float* w3 = (const float*)d_in[6];
    const float* b3 = (const float*)d_in[7];
    float* out = (float*)d_out;

    {
        const int total = NE * C2 * C1 * 9 + NE * C1 * 32 + NE * 9 * 16 * 32;
        repack_weights_kernel<<<(total + 255) / 256, 256, 0, stream>>>(w1, w2, w3);
    }
    {
        dim3 grid(HW / 16, HW / 16, 32);
        espcn_fused_kernel<<<grid, 512, 0, stream>>>(x, ci, b1, b2, b3, out);
    }
}